// Round 9
// baseline (418.455 us; speedup 1.0000x reference)
//
#include <hip/hip_runtime.h>
#include <hip/hip_bf16.h>
#include <stdint.h>

typedef unsigned short u16;
typedef __attribute__((ext_vector_type(8))) short short8;
typedef __attribute__((ext_vector_type(4))) float floatx4;

#define BT 200      // B*T
#define NOBJ 30
#define KP2 4224    // padded K: 6 z-slices x 11 iters x 64
#define DIN 4097
#define DH1 512
#define DH2 256
#define DFF 512
#define MPAD 6016
#define NBIGW (132*16)   // fold_big blocks
#define NSMALL 512
#define NCONV (BT*12)    // conv blocks: 3 chunk-parts x 4 n-slices per bt
#define NZERO 128

__device__ __forceinline__ u16 f2bf(float f) {
    union { float f; uint32_t u; } c; c.f = f;
    uint32_t u = c.u;
    u += 0x7FFF + ((u >> 16) & 1);
    return (u16)(u >> 16);
}

// async global->LDS DMA, 16B/lane; LDS dest is wave-uniform base + lane*16
__device__ __forceinline__ void load16_lds(const u16* g, u16* l) {
    __builtin_amdgcn_global_load_lds(
        (const __attribute__((address_space(1))) void*)g,
        (__attribute__((address_space(3))) void*)l, 16, 0, 0);
}

// tiled offset: tiles of 128 rows x (6 z x 11 iters x 64 k), storage
// [tile*6+z][i][row][slot]*8 ; slot = kw ^ (row&7)  (pre-swizzled)
__device__ __forceinline__ size_t tile_off(int ytile, int row, int c8) {
    int z = c8 / 88, rem = c8 - z * 88;
    int i = rem >> 3, kw = rem & 7;
    int ks = kw ^ (row & 7);
    return ((((size_t)(ytile * 6 + z) * 11 + i) * 128 + row) * 64) + ks * 8;
}

// ======== prep_all: fold_big | fold_small | conv (LDS-staged) | zero ========
__global__ void prep_all(const float* __restrict__ W1a, const float* __restrict__ W2a,
                         const float* __restrict__ W1b, const float* __restrict__ W2b,
                         const float* __restrict__ feat, const float* __restrict__ depth,
                         u16* __restrict__ Wc1T, u16* __restrict__ W2aTs,
                         u16* __restrict__ Wc2T, u16* __restrict__ W2bTs,
                         u16* __restrict__ XbT, u16* __restrict__ SbT,
                         float* __restrict__ zeroBase, size_t zeroQuads) {
    __shared__ __align__(16) char smem[32768];   // conv stage OR fold transpose
    int bid = blockIdx.x, tid = threadIdx.x;
    if (bid < NBIGW) {
        float (*t1)[33] = (float(*)[33])smem;            // 4224 B
        float (*t2)[33] = (float(*)[33])(smem + 4352);   // 4224 B
        int kb = (bid % 132) * 32, jb = (bid / 132) * 32;
        int tx = tid & 31, ty = tid >> 5;   // 32 x 8
        #pragma unroll
        for (int r = 0; r < 32; r += 8) {
            int k = kb + ty + r, j = jb + tx;
            float a = 0.f, b = 0.f;
            if (k < DIN) { a = W1a[k * DH1 + j]; b = W2a[k * DH1 + j]; }
            float bs = b * (1.f / 29.f);
            t1[ty + r][tx] = a - bs;
            t2[ty + r][tx] = bs;
        }
        __syncthreads();
        // one 16B chunk per thread: 2 arrays x 128 (32 j x 4 chunks)
        {
            int arr = tid >> 7, tt = tid & 127;
            int jrel = tt >> 2, ch = tt & 3;
            int j = jb + jrel;
            float (*src)[33] = arr ? t2 : t1;
            short8 o;
            #pragma unroll
            for (int e = 0; e < 8; e++) o[e] = (short)f2bf(src[ch * 8 + e][jrel]);
            int c8 = (kb >> 3) + ch;
            size_t off = tile_off(j >> 7, j & 127, c8);
            *(short8*)((arr ? W2aTs : Wc1T) + off) = o;
        }
    } else if (bid < NBIGW + NSMALL) {
        int idx = (bid - NBIGW) * 256 + tid;   // 256*512 total
        int j = idx >> 9, k = idx & 511;
        float a = W1b[k * DH2 + j];
        float b = W2b[k * DH2 + j] * (1.f / 29.f);
        Wc2T[j * DH1 + k]  = f2bf(a - b);
        W2bTs[j * DH1 + k] = f2bf(b);
    } else if (bid < NBIGW + NSMALL + NCONV) {
        u16* st = (u16*)smem;   // [8 rows][32 ci][8 kw][8 elems] u16 = 32 KB
        int cid = bid - NBIGW - NSMALL;
        int slice = cid & 3, part = (cid >> 2) % 3, bt = cid / 12;
        const int nsA[4] = {0, 8, 16, 23};
        const int neA[4] = {8, 16, 23, 30};
        int n0 = nsA[slice], ne = neA[slice], nrows = ne - n0;
        int nci = (part < 2) ? 32 : 2;          // part2 covers c8 512..527 only
        int c8 = part * 256 + tid;
        int valid = tid < nci * 8;
        if (valid) {
            int k8 = c8 * 8;
            float s[8] = {};
            int ci = tid >> 3, kw = tid & 7;
            for (int n = n0; n < ne; n++) {
                int r = bt * NOBJ + n;
                float v[8];
                if (k8 + 7 < 4096) {
                    float4 a = *(const float4*)(feat + (size_t)r * 4096 + k8);
                    float4 b = *(const float4*)(feat + (size_t)r * 4096 + k8 + 4);
                    v[0]=a.x; v[1]=a.y; v[2]=a.z; v[3]=a.w;
                    v[4]=b.x; v[5]=b.y; v[6]=b.z; v[7]=b.w;
                } else {
                    #pragma unroll
                    for (int e = 0; e < 8; e++) v[e] = 0.f;
                    if (k8 == 4096) v[0] = depth[r];
                }
                short8 o;
                #pragma unroll
                for (int e = 0; e < 8; e++) { s[e] += v[e]; o[e] = (short)f2bf(v[e]); }
                *(short8*)&st[(((size_t)(n - n0) * 32 + ci) * 8 + kw) * 8] = o;
            }
            short8 so;
            #pragma unroll
            for (int e = 0; e < 8; e++) so[e] = (short)f2bf(s[e]);
            int grow = slice * 256 + bt;   // partial-S row (4 slices of 256)
            *(short8*)(SbT + tile_off(grow >> 7, grow & 127, c8)) = so;
        }
        __syncthreads();
        // coalesced write-out: each wave covers one ci group (8 rows x 8 slots)
        int nchunks = nci * 64;
        for (int cidx = tid; cidx < nchunks; cidx += 256) {
            int ci = cidx >> 6, rem = cidx & 63;
            int rr = rem >> 3, s = rem & 7;
            if (rr >= nrows) continue;
            int r = bt * NOBJ + n0 + rr;
            int row = r & 127, tile = r >> 7;
            int c8g = part * 256 + ci * 8;
            int z = c8g / 88, i = (c8g % 88) >> 3;
            int kw = s ^ (row & 7);
            short8 val = *(short8*)&st[(((size_t)rr * 32 + ci) * 8 + kw) * 8];
            *(short8*)(XbT + ((((size_t)(tile * 6 + z) * 11 + i) * 128 + row) * 64 + s * 8)) = val;
        }
    } else {
        int zid = bid - NBIGW - NSMALL - NCONV;
        float4* p = (float4*)zeroBase;
        float4 zz = {0.f, 0.f, 0.f, 0.f};
        for (size_t idx = (size_t)zid * 256 + tid; idx < zeroQuads; idx += (size_t)NZERO * 256)
            p[idx] = zz;
    }
}

// ======== gemmA: 128x128 bf16 MFMA, contiguous tiled streams, split-K z=6 atomic ========
// seg0 (1128): hacc += XbT @ Wc1T   (M=6000, N=512, z=6 x 11 iters)
// seg1 ( 192): u    += SbT @ W2aTs  (4 partial slices, out row&255, z=6)
__global__ __launch_bounds__(256) void gemmA(
    const u16* __restrict__ XbT, const u16* __restrict__ WaT,
    const u16* __restrict__ SbT, const u16* __restrict__ WsT,
    float* __restrict__ hacc, float* __restrict__ uOut) {
    __shared__ __align__(16) u16 Al[8192];   // 16 KB
    __shared__ __align__(16) u16 Bl[8192];   // 16 KB
    int bid = blockIdx.x;
    const u16 *Abase, *Bbase;
    float* outF;
    int m0, n0, seg0 = bid < 1128;
    if (seg0) {
        int x = bid & 3, y = (bid >> 2) % 47, z = bid / 188;
        Abase = XbT + (size_t)((y * 6 + z) * 11) * 8192;
        Bbase = WaT + (size_t)((x * 6 + z) * 11) * 8192;
        outF = hacc; m0 = y * 128; n0 = x * 128;
    } else {
        int rem = bid - 1128;
        int x = rem & 3, y = (rem >> 2) & 7, z = rem >> 5;
        Abase = SbT + (size_t)((y * 6 + z) * 11) * 8192;
        Bbase = WsT + (size_t)((x * 6 + z) * 11) * 8192;
        outF = uOut; m0 = y * 128; n0 = x * 128;
    }
    int tid = threadIdx.x, lane = tid & 63, w = tid >> 6;
    floatx4 acc[4][4] = {};
    int lrow = lane & 15, q = lane >> 4;
    int wm = (w & 1) * 64, wn = (w >> 1) * 64;
    int swz = lrow & 7;

    for (int i = 0; i < 11; i++) {
        const u16* as = Abase + (size_t)i * 8192;
        const u16* bs = Bbase + (size_t)i * 8192;
        #pragma unroll
        for (int it = 0; it < 4; it++) {
            load16_lds(as + (it * 256 + tid) * 8, Al + it * 2048 + w * 512);
            load16_lds(bs + (it * 256 + tid) * 8, Bl + it * 2048 + w * 512);
        }
        __syncthreads();
        #pragma unroll
        for (int h = 0; h < 2; h++) {
            int so = ((h * 4 + q) ^ swz) * 8;
            short8 af[4], bfv[4];
            #pragma unroll
            for (int ii = 0; ii < 4; ii++)
                af[ii] = *(short8*)(Al + (wm + ii * 16 + lrow) * 64 + so);
            #pragma unroll
            for (int j = 0; j < 4; j++)
                bfv[j] = *(short8*)(Bl + (wn + j * 16 + lrow) * 64 + so);
            #pragma unroll
            for (int ii = 0; ii < 4; ii++)
                #pragma unroll
                for (int j = 0; j < 4; j++)
                    acc[ii][j] = __builtin_amdgcn_mfma_f32_16x16x32_bf16(af[ii], bfv[j], acc[ii][j], 0, 0, 0);
        }
        __syncthreads();
    }

    #pragma unroll
    for (int ii = 0; ii < 4; ii++)
        #pragma unroll
        for (int j = 0; j < 4; j++)
            #pragma unroll
            for (int r = 0; r < 4; r++) {
                int row = m0 + wm + ii * 16 + q * 4 + r;
                int col = n0 + wn + j * 16 + lrow;
                if (seg0) {
                    if (row < 6000)
                        atomicAdd(&outF[(size_t)row * DH1 + col], acc[ii][j][r]);
                } else {
                    int urow = row & 255;   // fold 4 partial slices into u[0..199]
                    if (urow < BT)
                        atomicAdd(&outF[(size_t)urow * DH1 + col], acc[ii][j][r]);
                }
            }
}

// ======== gemmB: 64x128 bf16 MFMA, BK=64, swizzle DMA, split-K z=4 atomic ========
__global__ __launch_bounds__(256) void gemmB(
    const u16* __restrict__ hb, const u16* __restrict__ Wc2T,
    const u16* __restrict__ Shb, const u16* __restrict__ W2bTs,
    float* __restrict__ hacc2, float* __restrict__ u2Out) {
    __shared__ __align__(16) u16 Al[64 * 64];    // 8 KB
    __shared__ __align__(16) u16 Bl[128 * 64];   // 16 KB
    int bid = blockIdx.x;
    const u16 *A, *B;
    float* outF;
    int m0, n0, kbeg, M;
    if (bid < 752) {
        int x = bid & 1, y = (bid >> 1) % 94, z = bid / 188;
        A = hb; B = Wc2T; outF = hacc2; M = 6000;
        m0 = y * 64; n0 = x * 128; kbeg = z * 128;
    } else {
        int rem = bid - 752;
        int x = rem & 1, y = (rem >> 1) & 3, z = rem >> 3;
        A = Shb; B = W2bTs; outF = u2Out; M = BT;
        m0 = y * 64; n0 = x * 128; kbeg = z * 128;
    }
    int kend = kbeg + 128;
    const int N = DH2, K = DH1;
    int tid = threadIdx.x;
    int lane = tid & 63, w = tid >> 6;
    int srow = tid >> 3, kslot = tid & 7;
    floatx4 acc[2][4] = {};
    int lrow = lane & 15, q = lane >> 4;
    int wm = (w & 1) * 32, wn = (w >> 1) * 64;
    int swz = lrow & 7;

    for (int kb = kbeg; kb < kend; kb += 64) {
        #pragma unroll
        for (int it = 0; it < 2; it++) {
            int row = it * 32 + srow;
            int kph = kslot ^ (row & 7);
            load16_lds(A + (size_t)(m0 + row) * K + kb + kph * 8,
                       Al + it * 2048 + w * 512);
        }
        #pragma unroll
        for (int it = 0; it < 4; it++) {
            int row = it * 32 + srow;
            int kph = kslot ^ (row & 7);
            load16_lds(B + (size_t)(n0 + row) * K + kb + kph * 8,
                       Bl + it * 2048 + w * 512);
        }
        __syncthreads();
        #pragma unroll
        for (int h = 0; h < 2; h++) {
            int so = ((h * 4 + q) ^ swz) * 8;
            short8 af[2], bfv[4];
            #pragma unroll
            for (int i = 0; i < 2; i++)
                af[i] = *(short8*)(Al + (wm + i * 16 + lrow) * 64 + so);
            #pragma unroll
            for (int j = 0; j < 4; j++)
                bfv[j] = *(short8*)(Bl + (wn + j * 16 + lrow) * 64 + so);
            #pragma unroll
            for (int i = 0; i < 2; i++)
                #pragma unroll
                for (int j = 0; j < 4; j++)
                    acc[i][j] = __builtin_amdgcn_mfma_f32_16x16x32_bf16(af[i], bfv[j], acc[i][j], 0, 0, 0);
        }
        __syncthreads();
    }

    #pragma unroll
    for (int i = 0; i < 2; i++)
        #pragma unroll
        for (int j = 0; j < 4; j++)
            #pragma unroll
            for (int r = 0; r < 4; r++) {
                int row = m0 + wm + i * 16 + q * 4 + r;
                int col = n0 + wn + j * 16 + lrow;
                if (row < M)
                    atomicAdd(&outF[(size_t)row * N + col], acc[i][j][r]);
            }
}

// -------- reduce1: h = relu(hacc + u + b1a) -> bf16 hb; node-sum -> Shb --------
__global__ void reduce1(const float* __restrict__ hacc, const float* __restrict__ u,
                        const float* __restrict__ b1a,
                        u16* __restrict__ hb, u16* __restrict__ Shb) {
    __shared__ float sl[128];
    int bt = blockIdx.x, c0 = blockIdx.y * 128;
    int lc = threadIdx.x & 127, rp = threadIdx.x >> 7;
    int col = c0 + lc;
    float ub = u[bt * DH1 + col] + b1a[col];
    float s = 0.f;
    for (int n = rp; n < NOBJ; n += 2) {
        float v = hacc[(size_t)(bt * NOBJ + n) * DH1 + col] + ub;
        v = v > 0.f ? v : 0.f;
        hb[(size_t)(bt * NOBJ + n) * DH1 + col] = f2bf(v);
        s += v;
    }
    if (rp == 0) sl[lc] = s;
    __syncthreads();
    if (rp == 1) Shb[bt * DH1 + col] = f2bf(sl[lc] + s);
}

// -------- reduce2_qkv: g = mean_n relu(hacc2 + u2 + b1b); q,k,v = g @ W --------
__global__ void reduce2_qkv(const float* __restrict__ hacc2, const float* __restrict__ u2,
                            const float* __restrict__ b1b,
                            const float* __restrict__ Wq, const float* __restrict__ Wk,
                            const float* __restrict__ Wv,
                            float* __restrict__ g, float* __restrict__ q,
                            float* __restrict__ k, float* __restrict__ v) {
    __shared__ float gl[DH2];
    int bt = blockIdx.x, j = threadIdx.x;
    float ub = u2[bt * DH2 + j] + b1b[j];
    float a = 0.f;
    for (int n = 0; n < NOBJ; n++) {
        float vv = hacc2[(size_t)(bt * NOBJ + n) * DH2 + j] + ub;
        a += vv > 0.f ? vv : 0.f;
    }
    a *= (1.f / 30.f);
    gl[j] = a;
    g[bt * DH2 + j] = a;
    __syncthreads();
    float aq = 0.f, ak = 0.f, av = 0.f;
    for (int kk = 0; kk < DH2; kk++) {
        float x = gl[kk];
        aq += x * Wq[kk * DH2 + j];
        ak += x * Wk[kk * DH2 + j];
        av += x * Wv[kk * DH2 + j];
    }
    q[bt * DH2 + j] = aq;
    k[bt * DH2 + j] = ak;
    v[bt * DH2 + j] = av;
}

// -------- fused attention + Wo + LN1 + FFN + LN2 + classifier --------
__device__ __forceinline__ float block_sum256(float v, volatile float* red) {
    #pragma unroll
    for (int o = 32; o > 0; o >>= 1) v += __shfl_down(v, o);
    int w = threadIdx.x >> 6;
    __syncthreads();
    if ((threadIdx.x & 63) == 0) red[w] = v;
    __syncthreads();
    return red[0] + red[1] + red[2] + red[3];
}

__global__ void attn_head(const float* __restrict__ qg, const float* __restrict__ kg,
                          const float* __restrict__ vg, const float* __restrict__ g,
                          const float* __restrict__ Wo,
                          const float* __restrict__ ln1g, const float* __restrict__ ln1b,
                          const float* __restrict__ Wf1, const float* __restrict__ bf1,
                          const float* __restrict__ Wf2, const float* __restrict__ bf2,
                          const float* __restrict__ ln2g, const float* __restrict__ ln2b,
                          const float* __restrict__ Wc, const float* __restrict__ bc,
                          float* __restrict__ out) {
    __shared__ float ql[DH2];
    __shared__ float scl[4][128];
    __shared__ float ctxl[DH2];
    __shared__ float yl[DH2];
    __shared__ float ffl[DFF];
    __shared__ float red[4];
    int row = blockIdx.x, tid = threadIdx.x;
    int base = (row >= 100) ? 100 : 0;
    ql[tid] = qg[row * DH2 + tid];
    __syncthreads();

    for (int p = tid; p < 512; p += 256) {
        int h = p >> 7, s = p & 127;
        if (s < 100) {
            const float* kr = kg + (size_t)(base + s) * DH2 + h * 64;
            float a = 0.f;
            #pragma unroll 8
            for (int d = 0; d < 64; d++) a += ql[h * 64 + d] * kr[d];
            scl[h][s] = a * 0.125f;
        }
    }
    __syncthreads();

    {
        int w = tid >> 6, lane = tid & 63;
        int s2 = 64 + lane;
        float a  = scl[w][lane];
        float b2 = (s2 < 100) ? scl[w][s2] : -1e30f;
        float m = fmaxf(a, b2);
        #pragma unroll
        for (int o = 32; o > 0; o >>= 1) m = fmaxf(m, __shfl_down(m, o));
        m = __shfl(m, 0);
        float e1 = __expf(a - m);
        float e2 = (s2 < 100) ? __expf(b2 - m) : 0.f;
        float sm = e1 + e2;
        #pragma unroll
        for (int o = 32; o > 0; o >>= 1) sm += __shfl_down(sm, o);
        sm = __shfl(sm, 0);
        float r = 1.f / sm;
        scl[w][lane] = e1 * r;
        if (s2 < 100) scl[w][s2] = e2 * r;
    }
    __syncthreads();

    {
        int h = tid >> 6;
        float o = 0.f;
        for (int s = 0; s < 100; s++)
            o += scl[h][s] * vg[(size_t)(base + s) * DH2 + tid];
        ctxl[tid] = o;
    }
    __syncthreads();

    float o = 0.f;
    for (int kk = 0; kk < DH2; kk++) o += ctxl[kk] * Wo[kk * DH2 + tid];
    float t = g[row * DH2 + tid] + o;
    float mu  = block_sum256(t, red) * (1.f / DH2);
    float ex2 = block_sum256(t * t, red) * (1.f / DH2);
    float y = (t - mu) * rsqrtf(ex2 - mu * mu + 1e-5f) * ln1g[tid] + ln1b[tid];
    yl[tid] = y;
    __syncthreads();
    for (int jj = tid; jj < DFF; jj += 256) {
        float a = bf1[jj];
        for (int kk = 0; kk < DH2; kk++) a += yl[kk] * Wf1[kk * DFF + jj];
        ffl[jj] = a > 0.f ? a : 0.f;
    }
    __syncthreads();
    float o2 = bf2[tid];
    for (int kk = 0; kk < DFF; kk++) o2 += ffl[kk] * Wf2[kk * DH2 + tid];
    float z0 = y + o2;
    float mu2  = block_sum256(z0, red) * (1.f / DH2);
    float ex22 = block_sum256(z0 * z0, red) * (1.f / DH2);
    float z = (z0 - mu2) * rsqrtf(ex22 - mu2 * mu2 + 1e-5f) * ln2g[tid] + ln2b[tid];
    float logit = block_sum256(z * Wc[tid], red) + bc[0];
    if (tid == 0) {
        out[row]      = 1.f / (1.f + __expf(-logit));
        out[BT + row] = 0.f;
    }
}

// ---------------- launch ----------------
extern "C" void kernel_launch(void* const* d_in, const int* in_sizes, int n_in,
                              void* d_out, int out_size, void* d_ws, size_t ws_size,
                              hipStream_t stream) {
    const float* feat  = (const float*)d_in[0];
    const float* depth = (const float*)d_in[1];
    const float* W1a = (const float*)d_in[2];
    const float* W2a = (const float*)d_in[3];
    const float* b1a = (const float*)d_in[4];
    const float* W1b = (const float*)d_in[5];
    const float* W2b = (const float*)d_in[6];
    const float* b1b = (const float*)d_in[7];
    const float* Wq  = (const float*)d_in[8];
    const float* Wk  = (const float*)d_in[9];
    const float* Wv  = (const float*)d_in[10];
    const float* Wo  = (const float*)d_in[11];
    const float* ln1g = (const float*)d_in[12];
    const float* ln1b = (const float*)d_in[13];
    const float* Wf1 = (const float*)d_in[14];
    const float* bf1 = (const float*)d_in[15];
    const float* Wf2 = (const float*)d_in[16];
    const float* bf2 = (const float*)d_in[17];
    const float* ln2g = (const float*)d_in[18];
    const float* ln2b = (const float*)d_in[19];
    const float* Wc  = (const float*)d_in[20];
    const float* bc  = (const float*)d_in[21];
    float* out = (float*)d_out;
    char* ws = (char*)d_ws;

    size_t off = 0;
    u16* XbT   = (u16*)(ws + off); off += (size_t)MPAD * KP2 * 2;    // 50.8 MB
    u16* SbT   = (u16*)(ws + off); off += (size_t)1024 * KP2 * 2;    //  8.65 MB
    u16* Wc1T  = (u16*)(ws + off); off += (size_t)DH1 * KP2 * 2;     //  4.3 MB
    u16* W2aTs = (u16*)(ws + off); off += (size_t)DH1 * KP2 * 2;
    u16* Wc2T  = (u16*)(ws + off); off += (size_t)DH2 * DH1 * 2;
    u16* W2bTs = (u16*)(ws + off); off += (size_t)DH2 * DH1 * 2;
    u16* Shb   = (u16*)(ws + off); off += (size_t)256 * DH1 * 2;
    // contiguous zero region (cleared by prep_all)
    char* zBase = ws + off;
    float* hacc  = (float*)(ws + off); off += (size_t)6000 * DH1 * 4;  // 12.3 MB
    float* hacc2 = (float*)(ws + off); off += (size_t)6000 * DH2 * 4;  //  6.1 MB
    float* u     = (float*)(ws + off); off += (size_t)256 * DH1 * 4;
    float* u2    = (float*)(ws + off); off += (size_t)256 * DH2 * 4;
    size_t zeroQuads = (size_t)(ws + off - zBase) / 16;
    // aliases: hb reuses XbT (dead after gemmA); g/q/k/v reuse SbT (dead after gemmA)
    u16* hb = XbT;
    float* g = (float*)SbT;
    float* q = g + BT * DH2;
    float* k = q + BT * DH2;
    float* v = k + BT * DH2;

    prep_all<<<NBIGW + NSMALL + NCONV + NZERO, 256, 0, stream>>>(
        W1a, W2a, W1b, W2b, feat, depth,
        Wc1T, W2aTs, Wc2T, W2bTs, XbT, SbT, (float*)zBase, zeroQuads);
    // hacc += XbT@Wc1T (1128 blocks, z=6) ; u += SbT@W2aTs (192 blocks)
    gemmA<<<1128 + 192, 256, 0, stream>>>(XbT, Wc1T, SbT, W2aTs, hacc, u);
    reduce1<<<dim3(BT, 4), 256, 0, stream>>>(hacc, u, b1a, hb, Shb);
    // hacc2 += hb@Wc2T (752 blocks, z=4) ; u2 += Shb@W2bTs (32 blocks, z=4)
    gemmB<<<752 + 32, 256, 0, stream>>>(hb, Wc2T, Shb, W2bTs, hacc2, u2);
    reduce2_qkv<<<BT, DH2, 0, stream>>>(hacc2, u2, b1b, Wq, Wk, Wv, g, q, k, v);
    attn_head<<<BT, DH2, 0, stream>>>(q, k, v, g, Wo, ln1g, ln1b, Wf1, bf1,
                                      Wf2, bf2, ln2g, ln2b, Wc, bc, out);
}